// Round 7
// baseline (656.768 us; speedup 1.0000x reference)
//
#include <hip/hip_runtime.h>

#define N_NODES 20000
#define D_IN    1000
#define E_EDGES 160000
#define DA      100

#define MP   20096    // 157 * 128 (padded rows)
#define DP   1024     // padded K / structural cols
#define DAP  128      // padded attr cols
#define MBLK 157
#define NRB  1250     // row-blocks per graph for spmm (16 rows/block)
#define PEMAX (E_EDGES + 4 * N_NODES)   // padded edge capacity (rows padded to x4)

typedef __bf16 bf16x8 __attribute__((ext_vector_type(8)));
typedef float  f32x4  __attribute__((ext_vector_type(4)));
typedef short  short8v __attribute__((ext_vector_type(8)));

__device__ __forceinline__ short f2bf(float f) {
  __bf16 h = (__bf16)f;                 // native RNE cvt
  return *(short*)&h;
}
__device__ __forceinline__ float bf2f(short s) {
  return __uint_as_float(((unsigned)(unsigned short)s) << 16);
}

#define GLDS16(g, l) __builtin_amdgcn_global_load_lds( \
    (const __attribute__((address_space(1))) void*)(g), \
    (__attribute__((address_space(3))) void*)(l), 16, 0, 0)

// ---------------------------------------------------------------- conversions

__global__ void cvt_pad2_k(const float* __restrict__ s0, const float* __restrict__ s1,
                           int R, int C,
                           short* __restrict__ d0, short* __restrict__ d1, int Cp) {
  const float* src = blockIdx.z ? s1 : s0;
  short* dst = blockIdx.z ? d1 : d0;
  int r = blockIdx.y;
  int c0 = threadIdx.x * 4;
  short4 o = {0, 0, 0, 0};
  if (r < R) {
    if (c0 + 3 < C) {
      float4 v = *(const float4*)&src[(size_t)r * C + c0];
      o.x = f2bf(v.x); o.y = f2bf(v.y); o.z = f2bf(v.z); o.w = f2bf(v.w);
    } else {
#pragma unroll
      for (int j = 0; j < 4; ++j) {
        float v = (c0 + j < C) ? src[(size_t)r * C + c0 + j] : 0.f;
        ((short*)&o)[j] = f2bf(v);
      }
    }
  }
  *(short4*)&dst[(size_t)r * Cp + c0] = o;
}

__global__ void cvt_w_t2_k(const float* __restrict__ s0, const float* __restrict__ s1,
                           int K, int Nc,
                           short* __restrict__ d0, short* __restrict__ d1, int Kp) {
  const float* src = blockIdx.z ? s1 : s0;
  short* dst = blockIdx.z ? d1 : d0;
  int n = blockIdx.y;
  int k = blockIdx.x * blockDim.x + threadIdx.x;
  if (k >= Kp) return;
  float v = (k < K && n < Nc) ? src[(size_t)k * Nc + n] : 0.f;
  dst[(size_t)n * Kp + k] = f2bf(v);
}

__global__ void zero_int_k(int* p, int n) {
  int i = blockIdx.x * blockDim.x + threadIdx.x;
  if (i < n) p[i] = 0;
}

// ---------------------------------------------------------------- CSR build (padded, both graphs)

__global__ void hist2_k(const int* __restrict__ row0, const int* __restrict__ row1, int E,
                        int* __restrict__ deg0, int* __restrict__ deg1) {
  int e = blockIdx.x * blockDim.x + threadIdx.x;
  if (e < E) atomicAdd(&deg0[row0[e]], 1);
  else if (e < 2 * E) atomicAdd(&deg1[row1[e - E]], 1);
}

#define SCAN_T 1024
#define SCAN_C 20
__launch_bounds__(SCAN_T)
__global__ void scan_pad2_k(const int* __restrict__ dg0, const int* __restrict__ dg1, int n,
                            int* __restrict__ p0, int* __restrict__ p1) {
  const int* deg = blockIdx.x ? dg1 : dg0;
  int* poffs = blockIdx.x ? p1 : p0;
  __shared__ int lds[SCAN_T];
  int t = threadIdx.x;
  int base = t * SCAN_C;
  int v[SCAN_C];
  int s = 0;
#pragma unroll
  for (int i = 0; i < SCAN_C; ++i) {
    int idx = base + i;
    int x = (idx < n) ? ((deg[idx] + 3) & ~3) : 0;
    s += x;
    v[i] = s;
  }
  lds[t] = s;
  __syncthreads();
  for (int off = 1; off < SCAN_T; off <<= 1) {
    int add = (t >= off) ? lds[t - off] : 0;
    __syncthreads();
    lds[t] += add;
    __syncthreads();
  }
  int prefix = lds[t] - s;
#pragma unroll
  for (int i = 0; i < SCAN_C; ++i) {
    int idx = base + i;
    if (idx < n) poffs[idx + 1] = v[i] + prefix;
  }
  if (t == 0) poffs[0] = 0;
}

__global__ void scatter_pack2_k(const int* __restrict__ row0, const int* __restrict__ col0,
                                const float* __restrict__ val0,
                                const int* __restrict__ row1, const int* __restrict__ col1,
                                const float* __restrict__ val1, int E,
                                const int* __restrict__ po0, const int* __restrict__ po1,
                                int* __restrict__ cur0, int* __restrict__ cur1,
                                int2* __restrict__ pk0, int2* __restrict__ pk1) {
  int e = blockIdx.x * blockDim.x + threadIdx.x;
  if (e < E) {
    int r = row0[e];
    int p = atomicAdd(&cur0[r], 1);
    pk0[po0[r] + p] = make_int2(col0[e], __float_as_int(val0[e]));
  } else if (e < 2 * E) {
    int ee = e - E;
    int r = row1[ee];
    int p = atomicAdd(&cur1[r], 1);
    pk1[po1[r] + p] = make_int2(col1[ee], __float_as_int(val1[ee]));
  }
}

// ---------------------------------------------------------------- big GEMM: counted-vmcnt pipeline
// C[M x 1024] = A[M x 1024] * Bt[1024 x 1024]^T, bf16, f32 accum, bf16 out.
// BM=128 BN=256 BK=32, 4 LDS buffers (96 KB), 512 thr = 8 waves (2x4), 64x64/wave.
// Per K-tile: {8 ds_read_b128 | stage tile t+3 (3 gload_lds) | s_barrier |
//              16 MFMA (setprio) | s_waitcnt vmcnt(6) | s_barrier}.
// T2 swizzle: 16B-chunk ^= (row>>1)&3 (both sides: pre-swizzled global source +
// swizzled ds_read addr; linear gload_lds dest). Race-free: tile t+3's buffer
// was last read at tile t-1, all reads consumed before the barrier we crossed.
template<int NT>
__launch_bounds__(512, 1)
__global__ void gemm_pipe_k(const short* __restrict__ A0, const short* __restrict__ A1, int lda,
                            const short* __restrict__ Bt0, const short* __restrict__ Bt1, int ldb,
                            short* __restrict__ C0, short* __restrict__ C1, int ldc,
                            int nbCol, int nbRow) {
  __shared__ short As[4][128 * 32];   // 32 KB
  __shared__ short Bs[4][256 * 32];   // 64 KB

  // XCD-aware bijective remap (cols fastest within chunk)
  int orig = blockIdx.x;
  int nwg = gridDim.x;
  int q = nwg >> 3, rr = nwg & 7;
  int xcd = orig & 7, idx = orig >> 3;
  int wg = (xcd < rr ? xcd * (q + 1) : rr * (q + 1) + (xcd - rr) * q) + idx;
  int colB = wg % nbCol;
  int t2 = wg / nbCol;
  int rowB = t2 % nbRow;
  int z = t2 / nbRow;

  const short* A  = z ? A1 : A0;
  const short* Bt = z ? Bt1 : Bt0;
  short* C        = z ? C1 : C0;

  const int tid  = threadIdx.x;
  const int lane = tid & 63;
  const int wid  = tid >> 6;
  const int wm   = wid >> 2;      // 0..1
  const int wn   = wid & 3;       // 0..3
  const int rowBase = rowB * 128;
  const int colBase = colB * 256;

  // staging: thread covers LDS row tid>>2, 16B chunk tid&3 (linear dest);
  // source chunk pre-swizzled: (tid&3) ^ ((row>>1)&3) = (tid&3) ^ ((tid>>3)&3)
  const int sRow   = tid >> 2;
  const int sChunk = (tid & 3) ^ ((tid >> 3) & 3);
  const short* gA  = A  + (size_t)(rowBase + sRow) * lda + sChunk * 8;
  const short* gB0 = Bt + (size_t)(colBase + sRow) * ldb + sChunk * 8;
  const short* gB1 = Bt + (size_t)(colBase + 128 + sRow) * ldb + sChunk * 8;
  const int ldsA  = wid * 512;          // wave-uniform base, shorts
  const int ldsB0 = wid * 512;
  const int ldsB1 = 4096 + wid * 512;

  // swizzled read addresses (shorts, within one buffer)
  int rA[4], rB[4];
#pragma unroll
  for (int m = 0; m < 4; ++m) {
    int row = wm * 64 + m * 16 + (lane & 15);
    int ch = (lane >> 4) ^ ((row >> 1) & 3);
    rA[m] = row * 32 + ch * 8;
  }
#pragma unroll
  for (int n = 0; n < 4; ++n) {
    int row = wn * 64 + n * 16 + (lane & 15);
    int ch = (lane >> 4) ^ ((row >> 1) & 3);
    rB[n] = row * 32 + ch * 8;
  }

  f32x4 acc[4][4];
#pragma unroll
  for (int m = 0; m < 4; ++m)
#pragma unroll
    for (int n = 0; n < 4; ++n)
      acc[m][n] = (f32x4){0.f, 0.f, 0.f, 0.f};

#define STAGE_T(kt, b) do { \
    GLDS16(gA  + (kt) * 32, &As[b][ldsA]);  \
    GLDS16(gB0 + (kt) * 32, &Bs[b][ldsB0]); \
    GLDS16(gB1 + (kt) * 32, &Bs[b][ldsB1]); \
  } while (0)

  // prologue: 3-deep prefetch
  STAGE_T(0, 0);
  STAGE_T(1, 1);
  STAGE_T(2, 2);
  asm volatile("s_waitcnt vmcnt(6)" ::: "memory");   // tile 0 landed
  __builtin_amdgcn_s_barrier();
  __builtin_amdgcn_sched_barrier(0);

  for (int t = 0; t < NT; ++t) {
    const int buf = t & 3;
    const short* pa = &As[buf][0];
    const short* pb = &Bs[buf][0];
    bf16x8 af[4], bfr[4];
#pragma unroll
    for (int m = 0; m < 4; ++m) af[m] = *(const bf16x8*)&pa[rA[m]];
#pragma unroll
    for (int n = 0; n < 4; ++n) bfr[n] = *(const bf16x8*)&pb[rB[n]];
    if (t + 3 < NT) STAGE_T(t + 3, (t + 3) & 3);
    __builtin_amdgcn_s_barrier();
    __builtin_amdgcn_s_setprio(1);
#pragma unroll
    for (int m = 0; m < 4; ++m)
#pragma unroll
      for (int n = 0; n < 4; ++n)
        acc[m][n] = __builtin_amdgcn_mfma_f32_16x16x32_bf16(af[m], bfr[n], acc[m][n], 0, 0, 0);
    __builtin_amdgcn_s_setprio(0);
    // counted wait: next tile landed, 2 more stay in flight (never 0 mid-loop)
    if (t < NT - 3)       { asm volatile("s_waitcnt vmcnt(6)" ::: "memory"); }
    else if (t == NT - 3) { asm volatile("s_waitcnt vmcnt(3)" ::: "memory"); }
    else if (t == NT - 2) { asm volatile("s_waitcnt vmcnt(0)" ::: "memory"); }
    __builtin_amdgcn_s_barrier();
    __builtin_amdgcn_sched_barrier(0);
  }
#undef STAGE_T

#pragma unroll
  for (int m = 0; m < 4; ++m) {
#pragma unroll
    for (int n = 0; n < 4; ++n) {
      int r0 = rowBase + wm * 64 + m * 16 + (lane >> 4) * 4;
      int c  = colBase + wn * 64 + n * 16 + (lane & 15);
#pragma unroll
      for (int reg = 0; reg < 4; ++reg)
        C[(size_t)(r0 + reg) * ldc + c] = f2bf(acc[m][n][reg]);
    }
  }
}

// ---------------------------------------------------------------- small GEMM (128x128, attr branch)
__launch_bounds__(256, 2)
__global__ void gemm_bf16_k(const short* __restrict__ A0, const short* __restrict__ A1, int lda,
                            const short* __restrict__ Bt0, const short* __restrict__ Bt1, int ldb,
                            short* __restrict__ C0, short* __restrict__ C1, int ldc, int K,
                            int nbCol, int nbRow) {
  __shared__ short As[128 * 64];
  __shared__ short Bs[128 * 64];

  int orig = blockIdx.x;
  int nwg = gridDim.x;
  int q = nwg >> 3, rr = nwg & 7;
  int xcd = orig & 7, idx = orig >> 3;
  int wg = (xcd < rr ? xcd * (q + 1) : rr * (q + 1) + (xcd - rr) * q) + idx;
  int colB = wg % nbCol;
  int t2   = wg / nbCol;
  int rowB = t2 % nbRow;
  int z    = t2 / nbRow;

  const short* A  = z ? A1 : A0;
  const short* Bt = z ? Bt1 : Bt0;
  short* C        = z ? C1 : C0;

  const int tid  = threadIdx.x;
  const int lane = tid & 63;
  const int wid  = tid >> 6;
  const int wr   = wid >> 1;
  const int wc   = wid & 1;
  const int rowBase = rowB * 128;
  const int colBase = colB * 128;

  const int lrow = lane >> 3;
  const int kofs = (lane & 7) * 8;

  f32x4 acc[4][4];
#pragma unroll
  for (int m = 0; m < 4; ++m)
#pragma unroll
    for (int n = 0; n < 4; ++n)
      acc[m][n] = (f32x4){0.f, 0.f, 0.f, 0.f};

  for (int k0 = 0; k0 < K; k0 += 64) {
#pragma unroll
    for (int c = 0; c < 4; ++c) {
      int chunk = wid * 4 + c;
      int r = chunk * 8 + lrow;
      const short* g = A + (size_t)(rowBase + r) * lda + k0 + kofs;
      GLDS16(g, &As[chunk * 8 * 64]);
    }
#pragma unroll
    for (int c = 0; c < 4; ++c) {
      int chunk = wid * 4 + c;
      int r = chunk * 8 + lrow;
      const short* g = Bt + (size_t)(colBase + r) * ldb + k0 + kofs;
      GLDS16(g, &Bs[chunk * 8 * 64]);
    }
    __syncthreads();

    bf16x8 af[2][4], bfr[2][4];
#pragma unroll
    for (int kk = 0; kk < 2; ++kk) {
#pragma unroll
      for (int i = 0; i < 4; ++i) {
        int ar = wr * 64 + i * 16 + (lane & 15);
        af[kk][i]  = *(const bf16x8*)&As[ar * 64 + kk * 32 + (lane >> 4) * 8];
        int br = wc * 64 + i * 16 + (lane & 15);
        bfr[kk][i] = *(const bf16x8*)&Bs[br * 64 + kk * 32 + (lane >> 4) * 8];
      }
    }
#pragma unroll
    for (int kk = 0; kk < 2; ++kk)
#pragma unroll
      for (int m = 0; m < 4; ++m)
#pragma unroll
        for (int n = 0; n < 4; ++n)
          acc[m][n] = __builtin_amdgcn_mfma_f32_16x16x32_bf16(
              af[kk][m], bfr[kk][n], acc[m][n], 0, 0, 0);
    __syncthreads();
  }

#pragma unroll
  for (int m = 0; m < 4; ++m) {
#pragma unroll
    for (int n = 0; n < 4; ++n) {
      int row0 = rowBase + wr * 64 + m * 16 + (lane >> 4) * 4;
      int col  = colBase + wc * 64 + n * 16 + (lane & 15);
#pragma unroll
      for (int reg = 0; reg < 4; ++reg)
        C[(size_t)(row0 + reg) * ldc + col] = f2bf(acc[m][n][reg]);
    }
  }
}

// ---------------------------------------------------------------- SpMM + ReLU (v5: col-chunked, XCD-pinned)
template<int NCHUNK, int MODE>
__launch_bounds__(256)
__global__ void spmm_v5(const int* __restrict__ po0, const int* __restrict__ po1,
                        const int2* __restrict__ pk0, const int2* __restrict__ pk1,
                        const short* __restrict__ S0, const short* __restrict__ S1, int ldS,
                        short* __restrict__ oB0, short* __restrict__ oB1, int ldB,
                        float* __restrict__ oF0, float* __restrict__ oF1, int outCols) {
  int orig = blockIdx.x;
  int chunk, graph, rowBlk;
  if (NCHUNK == 8) {
    chunk = orig & 7;
    int idx = orig >> 3;
    graph = idx / NRB;
    rowBlk = idx - graph * NRB;
  } else {
    chunk = 0;
    graph = orig / NRB;
    rowBlk = orig - graph * NRB;
  }
  const int* poffs   = graph ? po1 : po0;
  const int2* packed = graph ? pk1 : pk0;
  const short* S     = graph ? S1 : S0;
  short* outB        = graph ? oB1 : oB0;
  float* outF        = graph ? oF1 : oF0;

  const int lane16 = threadIdx.x & 15;
  const int rowloc = threadIdx.x >> 4;
  const int r  = rowBlk * 16 + rowloc;
  const int c0 = chunk * 128 + lane16 * 8;

  int e0 = poffs[r], e1 = poffs[r + 1];
  float acc[8];
#pragma unroll
  for (int j = 0; j < 8; ++j) acc[j] = 0.f;

  for (int i = e0; i < e1; i += 4) {
    const int4* p4 = (const int4*)&packed[i];
    int4 a = p4[0];
    int4 b = p4[1];
    short8v s0 = *(const short8v*)&S[(size_t)a.x * ldS + c0];
    short8v s1 = *(const short8v*)&S[(size_t)a.z * ldS + c0];
    short8v s2 = *(const short8v*)&S[(size_t)b.x * ldS + c0];
    short8v s3 = *(const short8v*)&S[(size_t)b.z * ldS + c0];
    float v0 = __int_as_float(a.y);
    float v1 = __int_as_float(a.w);
    float v2 = __int_as_float(b.y);
    float v3 = __int_as_float(b.w);
#pragma unroll
    for (int j = 0; j < 8; ++j) {
      acc[j] += v0 * bf2f(s0[j]);
      acc[j] += v1 * bf2f(s1[j]);
      acc[j] += v2 * bf2f(s2[j]);
      acc[j] += v3 * bf2f(s3[j]);
    }
  }
#pragma unroll
  for (int j = 0; j < 8; ++j) acc[j] = fmaxf(acc[j], 0.f);

  if (MODE == 0) {
    short8v o;
#pragma unroll
    for (int j = 0; j < 8; ++j) o[j] = f2bf(acc[j]);
    *(short8v*)&outB[(size_t)r * ldB + c0] = o;
  } else {
#pragma unroll
    for (int j = 0; j < 8; ++j)
      if (c0 + j < outCols)
        outF[(size_t)r * outCols + c0 + j] = acc[j];
  }
}

// ---------------------------------------------------------------- row l2 norm (z=2)
__global__ void l2norm2_k(const short* __restrict__ H0, const short* __restrict__ H1, int ldH,
                          float* __restrict__ o0, float* __restrict__ o1, int cols) {
  const short* H = blockIdx.y ? H1 : H0;
  float* out = blockIdx.y ? o1 : o0;
  __shared__ float red[4];
  int r = blockIdx.x;
  int t = threadIdx.x;
  float s = 0.f;
  for (int c = t; c < ldH; c += 256) {
    float v = bf2f(H[(size_t)r * ldH + c]);
    s += v * v;
  }
  for (int off = 32; off >= 1; off >>= 1) s += __shfl_down(s, off, 64);
  if ((t & 63) == 0) red[t >> 6] = s;
  __syncthreads();
  float tot = red[0] + red[1] + red[2] + red[3];
  float inv = 1.f / fmaxf(sqrtf(tot), 1e-12f);
  for (int c = t; c < cols; c += 256)
    out[(size_t)r * cols + c] = bf2f(H[(size_t)r * ldH + c]) * inv;
}

// ---------------------------------------------------------------- launch

extern "C" void kernel_launch(void* const* d_in, const int* in_sizes, int n_in,
                              void* d_out, int out_size, void* d_ws, size_t ws_size,
                              hipStream_t stream) {
  const float* emb_sr  = (const float*)d_in[0];
  const float* emb_tg  = (const float*)d_in[1];
  const float* attr_sr = (const float*)d_in[2];
  const float* attr_tg = (const float*)d_in[3];
  const int*   row_sr  = (const int*)d_in[4];
  const int*   col_sr  = (const int*)d_in[5];
  const float* vals_sr = (const float*)d_in[6];
  const int*   row_tg  = (const int*)d_in[7];
  const int*   col_tg  = (const int*)d_in[8];
  const float* vals_tg = (const float*)d_in[9];
  const float* W_s0    = (const float*)d_in[10];
  const float* W_s1    = (const float*)d_in[11];
  const float* W_a11   = (const float*)d_in[12];
  const float* W_a12   = (const float*)d_in[13];
  const float* W_a2    = (const float*)d_in[14];

  const int N = N_NODES, Dd = D_IN, E = E_EDGES;

  char* ws = (char*)d_ws;
  size_t off = 0;
  auto alloc = [&](size_t bytes) -> void* {
    void* p = ws + off;
    off += (bytes + 255) & ~(size_t)255;
    return p;
  };
  short* X0 = (short*)alloc((size_t)MP * DP * 2);
  short* X1 = (short*)alloc((size_t)MP * DP * 2);
  short* T0 = (short*)alloc((size_t)MP * DP * 2);
  short* T1 = (short*)alloc((size_t)MP * DP * 2);
  short* Ws0t  = (short*)alloc((size_t)DP * DP * 2);
  short* Ws1t  = (short*)alloc((size_t)DP * DP * 2);
  short* Wa11t = (short*)alloc((size_t)DAP * DP * 2);
  short* Wa12t = (short*)alloc((size_t)DAP * DP * 2);
  short* Wa2t  = (short*)alloc((size_t)DAP * DAP * 2);
  int*  ibuf    = (int*)alloc((size_t)4 * N * 4);
  int2* pack_sr = (int2*)alloc((size_t)PEMAX * 8);
  int2* pack_tg = (int2*)alloc((size_t)PEMAX * 8);
  int*  poffs_sr = (int*)alloc((size_t)(N + 1) * 4);
  int*  poffs_tg = (int*)alloc((size_t)(N + 1) * 4);
  if (off > ws_size) return;

  int* deg_sr = ibuf;
  int* cur_sr = ibuf + N;
  int* deg_tg = ibuf + 2 * N;
  int* cur_tg = ibuf + 3 * N;
  const int ZERO_N = 4 * N + 2 * (PEMAX * 2);

  float* out_sr  = (float*)d_out;
  float* out_tg  = out_sr + (size_t)N * Dd;
  float* out_sra = out_tg + (size_t)N * Dd;
  float* out_tga = out_sra + (size_t)N * DA;

  // ---- padded-CSR build, both graphs batched
  zero_int_k<<<dim3((ZERO_N + 255) / 256), 256, 0, stream>>>(ibuf, ZERO_N);
  hist2_k<<<dim3((2 * E + 255) / 256), 256, 0, stream>>>(row_sr, row_tg, E, deg_sr, deg_tg);
  scan_pad2_k<<<2, SCAN_T, 0, stream>>>(deg_sr, deg_tg, N, poffs_sr, poffs_tg);
  scatter_pack2_k<<<dim3((2 * E + 255) / 256), 256, 0, stream>>>(
      row_sr, col_sr, vals_sr, row_tg, col_tg, vals_tg, E,
      poffs_sr, poffs_tg, cur_sr, cur_tg, pack_sr, pack_tg);

  // ---- weight conversions (transposed + padded), batched
  cvt_w_t2_k<<<dim3(DP / 256, DP, 2), 256, 0, stream>>>(W_s0, W_s1, Dd, Dd, Ws0t, Ws1t, DP);
  cvt_w_t2_k<<<dim3(DP / 256, DAP, 2), 256, 0, stream>>>(W_a11, W_a12, Dd, DA, Wa11t, Wa12t, DP);
  cvt_w_t2_k<<<dim3(1, DAP, 1), 256, 0, stream>>>(W_a2, W_a2, DA, DA, Wa2t, Wa2t, DAP);

  // ---- structural branch (pipelined GEMM: 157x4x2 = 1256 blocks, %8==0)
  cvt_pad2_k<<<dim3(1, MP, 2), 256, 0, stream>>>(emb_sr, emb_tg, N, Dd, X0, X1, DP);
  gemm_pipe_k<32><<<dim3(MBLK * 4 * 2), 512, 0, stream>>>(X0, X1, DP, Ws0t, Ws0t, DP,
                                                          T0, T1, DP, 4, MBLK);
  spmm_v5<8, 0><<<dim3(8 * 2 * NRB), 256, 0, stream>>>(
      poffs_sr, poffs_tg, pack_sr, pack_tg, T0, T1, DP, X0, X1, DP, nullptr, nullptr, 0);
  gemm_pipe_k<32><<<dim3(MBLK * 4 * 2), 512, 0, stream>>>(X0, X1, DP, Ws1t, Ws1t, DP,
                                                          T0, T1, DP, 4, MBLK);
  spmm_v5<8, 0><<<dim3(8 * 2 * NRB), 256, 0, stream>>>(
      poffs_sr, poffs_tg, pack_sr, pack_tg, T0, T1, DP, X0, X1, DP, nullptr, nullptr, 0);
  l2norm2_k<<<dim3(N, 2), 256, 0, stream>>>(X0, X1, DP, out_sr, out_tg, Dd);

  // ---- attribute branch (compact stride DAP after first GEMM)
  cvt_pad2_k<<<dim3(1, MP, 2), 256, 0, stream>>>(attr_sr, attr_tg, N, Dd, X0, X1, DP);
  gemm_bf16_k<<<dim3(1 * MBLK * 2), 256, 0, stream>>>(X0, X1, DP, Wa11t, Wa12t, DP,
                                                      T0, T1, DAP, DP, 1, MBLK);
  spmm_v5<1, 0><<<dim3(2 * NRB), 256, 0, stream>>>(
      poffs_sr, poffs_tg, pack_sr, pack_tg, T0, T1, DAP, X0, X1, DAP, nullptr, nullptr, 0);
  gemm_bf16_k<<<dim3(1 * MBLK * 2), 256, 0, stream>>>(X0, X1, DAP, Wa2t, Wa2t, DAP,
                                                      T0, T1, DAP, DAP, 1, MBLK);
  spmm_v5<1, 1><<<dim3(2 * NRB), 256, 0, stream>>>(
      poffs_sr, poffs_tg, pack_sr, pack_tg, T0, T1, DAP, nullptr, nullptr, 0, out_sra, out_tga, DA);
}

// Round 8
// 636.919 us; speedup vs baseline: 1.0312x; 1.0312x over previous
//
#include <hip/hip_runtime.h>

#define N_NODES 20000
#define D_IN    1000
#define E_EDGES 160000
#define DA      100

#define MPAD 20224    // 79 * 256 (padded rows for 256-tile GEMM)
#define DP   1024     // padded K / structural cols
#define DAP  128      // padded attr cols
#define MBLK 157      // 128-row blocks for attr gemm (157*128 = 20096 <= MPAD)
#define NRB  1250     // row-blocks per graph for spmm (16 rows/block)
#define PEMAX (E_EDGES + 4 * N_NODES)   // padded edge capacity (rows padded to x4)

typedef __bf16 bf16x8 __attribute__((ext_vector_type(8)));
typedef float  f32x4  __attribute__((ext_vector_type(4)));
typedef short  short8v __attribute__((ext_vector_type(8)));

__device__ __forceinline__ short f2bf(float f) {
  __bf16 h = (__bf16)f;                 // native RNE cvt
  return *(short*)&h;
}
__device__ __forceinline__ float bf2f(short s) {
  return __uint_as_float(((unsigned)(unsigned short)s) << 16);
}

#define GLDS16(g, l) __builtin_amdgcn_global_load_lds( \
    (const __attribute__((address_space(1))) void*)(g), \
    (__attribute__((address_space(3))) void*)(l), 16, 0, 0)

// ---------------------------------------------------------------- conversions

__global__ void cvt_pad2_k(const float* __restrict__ s0, const float* __restrict__ s1,
                           int R, int C,
                           short* __restrict__ d0, short* __restrict__ d1, int Cp) {
  const float* src = blockIdx.z ? s1 : s0;
  short* dst = blockIdx.z ? d1 : d0;
  int r = blockIdx.y;
  int c0 = threadIdx.x * 4;
  short4 o = {0, 0, 0, 0};
  if (r < R) {
    if (c0 + 3 < C) {
      float4 v = *(const float4*)&src[(size_t)r * C + c0];
      o.x = f2bf(v.x); o.y = f2bf(v.y); o.z = f2bf(v.z); o.w = f2bf(v.w);
    } else {
#pragma unroll
      for (int j = 0; j < 4; ++j) {
        float v = (c0 + j < C) ? src[(size_t)r * C + c0 + j] : 0.f;
        ((short*)&o)[j] = f2bf(v);
      }
    }
  }
  *(short4*)&dst[(size_t)r * Cp + c0] = o;
}

__global__ void cvt_w_t2_k(const float* __restrict__ s0, const float* __restrict__ s1,
                           int K, int Nc,
                           short* __restrict__ d0, short* __restrict__ d1, int Kp) {
  const float* src = blockIdx.z ? s1 : s0;
  short* dst = blockIdx.z ? d1 : d0;
  int n = blockIdx.y;
  int k = blockIdx.x * blockDim.x + threadIdx.x;
  if (k >= Kp) return;
  float v = (k < K && n < Nc) ? src[(size_t)k * Nc + n] : 0.f;
  dst[(size_t)n * Kp + k] = f2bf(v);
}

__global__ void zero_int_k(int* p, int n) {
  int i = blockIdx.x * blockDim.x + threadIdx.x;
  if (i < n) p[i] = 0;
}

// ---------------------------------------------------------------- CSR build (padded, both graphs)

__global__ void hist2_k(const int* __restrict__ row0, const int* __restrict__ row1, int E,
                        int* __restrict__ deg0, int* __restrict__ deg1) {
  int e = blockIdx.x * blockDim.x + threadIdx.x;
  if (e < E) atomicAdd(&deg0[row0[e]], 1);
  else if (e < 2 * E) atomicAdd(&deg1[row1[e - E]], 1);
}

#define SCAN_T 1024
#define SCAN_C 20
__launch_bounds__(SCAN_T)
__global__ void scan_pad2_k(const int* __restrict__ dg0, const int* __restrict__ dg1, int n,
                            int* __restrict__ p0, int* __restrict__ p1) {
  const int* deg = blockIdx.x ? dg1 : dg0;
  int* poffs = blockIdx.x ? p1 : p0;
  __shared__ int lds[SCAN_T];
  int t = threadIdx.x;
  int base = t * SCAN_C;
  int v[SCAN_C];
  int s = 0;
#pragma unroll
  for (int i = 0; i < SCAN_C; ++i) {
    int idx = base + i;
    int x = (idx < n) ? ((deg[idx] + 3) & ~3) : 0;
    s += x;
    v[i] = s;
  }
  lds[t] = s;
  __syncthreads();
  for (int off = 1; off < SCAN_T; off <<= 1) {
    int add = (t >= off) ? lds[t - off] : 0;
    __syncthreads();
    lds[t] += add;
    __syncthreads();
  }
  int prefix = lds[t] - s;
#pragma unroll
  for (int i = 0; i < SCAN_C; ++i) {
    int idx = base + i;
    if (idx < n) poffs[idx + 1] = v[i] + prefix;
  }
  if (t == 0) poffs[0] = 0;
}

__global__ void scatter_pack2_k(const int* __restrict__ row0, const int* __restrict__ col0,
                                const float* __restrict__ val0,
                                const int* __restrict__ row1, const int* __restrict__ col1,
                                const float* __restrict__ val1, int E,
                                const int* __restrict__ po0, const int* __restrict__ po1,
                                int* __restrict__ cur0, int* __restrict__ cur1,
                                int2* __restrict__ pk0, int2* __restrict__ pk1) {
  int e = blockIdx.x * blockDim.x + threadIdx.x;
  if (e < E) {
    int r = row0[e];
    int p = atomicAdd(&cur0[r], 1);
    pk0[po0[r] + p] = make_int2(col0[e], __float_as_int(val0[e]));
  } else if (e < 2 * E) {
    int ee = e - E;
    int r = row1[ee];
    int p = atomicAdd(&cur1[r], 1);
    pk1[po1[r] + p] = make_int2(col1[ee], __float_as_int(val1[ee]));
  }
}

// ---------------------------------------------------------------- 8-phase 256x256 GEMM (structural)
// C[M x 1024] = A[M x 1024] * Bt[1024 x 1024]^T, bf16, f32 accum, bf16 out.
// 512 thr = 8 waves (2M x 4N), 128x64 out/wave, BK=64, 16 K-tiles.
// LDS: 8 half-slots x 16 KB (A-ks / B-ks x double-buffer cycle of 8).
// Half-tile stream H_k: tile t = k>>2, {A-ks0,B-ks0,A-ks1,B-ks1} = k&3.
// H_k staged at global phase k-4, waited by per-phase vmcnt(6) at phase k-1
// + barrier -> visible at its first use (phase >= k). Slot's previous
// occupant H_{k-8} dies >= 2 phases before the overwrite. Swizzle:
// 16B-chunk ^= (row>>1)&3 on both stage-source and ds_read (involution).
__launch_bounds__(512, 1)
__global__ void gemm8p_k(const short* __restrict__ A0, const short* __restrict__ A1, int lda,
                         const short* __restrict__ Bt0, const short* __restrict__ Bt1, int ldb,
                         short* __restrict__ C0, short* __restrict__ C1, int ldc,
                         int nbCol, int nbRow) {
  __shared__ short lds[8][8192];   // 8 x 16 KB = 128 KB

  // XCD-aware bijective remap (cols fastest within chunk)
  int orig = blockIdx.x;
  int nwg = gridDim.x;
  int q = nwg >> 3, rr = nwg & 7;
  int xcd = orig & 7, idx = orig >> 3;
  int wg = (xcd < rr ? xcd * (q + 1) : rr * (q + 1) + (xcd - rr) * q) + idx;
  int colB = wg % nbCol;
  int t2 = wg / nbCol;
  int rowB = t2 % nbRow;
  int z = t2 / nbRow;

  const short* A  = z ? A1 : A0;
  const short* Bt = z ? Bt1 : Bt0;
  short* C        = z ? C1 : C0;

  const int tid  = threadIdx.x;
  const int lane = tid & 63;
  const int wid  = tid >> 6;
  const int wm   = wid >> 2;      // 0..1
  const int wn   = wid & 3;       // 0..3
  const int rowBase = rowB * 256;
  const int colBase = colB * 256;

  // stage source (per thread): LDS region (wid*2+i)*16 rows; lane -> row l>>2,
  // chunk l&3 (linear dest). source chunk pre-swizzled: (l&3) ^ ((l>>3)&3)
  const int sC = (lane & 3) ^ ((lane >> 3) & 3);
  const short* baseA = A  + (size_t)(rowBase + wid * 32 + (lane >> 2)) * lda + sC * 8;
  const short* baseB = Bt + (size_t)(colBase + wid * 32 + (lane >> 2)) * ldb + sC * 8;

  // read-side swizzled offsets (shorts within a 16 KB slot: [256 rows][32 cols])
  const int chunkR = (lane >> 4) ^ ((lane >> 1) & 3);
  const int offA = (wm * 128 + (lane & 15)) * 32 + chunkR * 8;
  const int offB = (wn * 64  + (lane & 15)) * 32 + chunkR * 8;

  f32x4 acc[8][4];
#pragma unroll
  for (int m = 0; m < 8; ++m)
#pragma unroll
    for (int n = 0; n < 4; ++n)
      acc[m][n] = (f32x4){0.f, 0.f, 0.f, 0.f};

#define STAGE_HALF(h) do { \
    int tt_ = (h) >> 2; \
    int kc_ = tt_ * 64 + (((h) >> 1) & 1) * 32; \
    short* dst_ = &lds[(h) & 7][wid * 1024]; \
    if ((h) & 1) { GLDS16(baseB + kc_, dst_); GLDS16(baseB + kc_ + 16 * ldb, dst_ + 512); } \
    else         { GLDS16(baseA + kc_, dst_); GLDS16(baseA + kc_ + 16 * lda, dst_ + 512); } \
  } while (0)

  // prologue: stage H0..H4, wait for H0,H1 (leave 6 in flight)
  STAGE_HALF(0); STAGE_HALF(1); STAGE_HALF(2); STAGE_HALF(3); STAGE_HALF(4);
  asm volatile("s_waitcnt vmcnt(6)" ::: "memory");
  __builtin_amdgcn_s_barrier();
  __builtin_amdgcn_sched_barrier(0);

#define PHASE(P, KS, QM) do { \
    const int sA_ = (4 * t + 2 * (KS)) & 7; \
    const short* pA_ = &lds[sA_][0]; \
    const short* pB_ = &lds[sA_ + 1][0]; \
    bf16x8 af_[4], bv_[4]; \
    _Pragma("unroll") \
    for (int m = 0; m < 4; ++m) af_[m] = *(const bf16x8*)&pA_[offA + ((QM) * 4 + m) * 512]; \
    _Pragma("unroll") \
    for (int n = 0; n < 4; ++n) bv_[n] = *(const bf16x8*)&pB_[offB + n * 512]; \
    { int h_ = 4 * t + (P) + 5; \
      if (h_ < 64) STAGE_HALF(h_); } \
    __builtin_amdgcn_s_barrier(); \
    __builtin_amdgcn_s_setprio(1); \
    _Pragma("unroll") \
    for (int m = 0; m < 4; ++m) \
      _Pragma("unroll") \
      for (int n = 0; n < 4; ++n) \
        acc[(QM) * 4 + m][n] = __builtin_amdgcn_mfma_f32_16x16x32_bf16( \
            af_[m], bv_[n], acc[(QM) * 4 + m][n], 0, 0, 0); \
    __builtin_amdgcn_s_setprio(0); \
    if (t < 14)      { asm volatile("s_waitcnt vmcnt(6)" ::: "memory"); } \
    else if (t == 14) { \
      if ((P) < 3)   { asm volatile("s_waitcnt vmcnt(6)" ::: "memory"); } \
      else           { asm volatile("s_waitcnt vmcnt(4)" ::: "memory"); } \
    } else { \
      if ((P) == 0)  { asm volatile("s_waitcnt vmcnt(2)" ::: "memory"); } \
      else           { asm volatile("s_waitcnt vmcnt(0)" ::: "memory"); } \
    } \
    __builtin_amdgcn_s_barrier(); \
    __builtin_amdgcn_sched_barrier(0); \
  } while (0)

  for (int t = 0; t < 16; ++t) {
    PHASE(0, 0, 0);
    PHASE(1, 0, 1);
    PHASE(2, 1, 0);
    PHASE(3, 1, 1);
  }
#undef PHASE
#undef STAGE_HALF

  // C write: frag gm (0..7), n (0..3); D layout col=lane&15, row=(lane>>4)*4+reg
#pragma unroll
  for (int gm = 0; gm < 8; ++gm) {
#pragma unroll
    for (int n = 0; n < 4; ++n) {
      int r0 = rowBase + wm * 128 + gm * 16 + (lane >> 4) * 4;
      int c  = colBase + wn * 64 + n * 16 + (lane & 15);
#pragma unroll
      for (int reg = 0; reg < 4; ++reg)
        C[(size_t)(r0 + reg) * ldc + c] = f2bf(acc[gm][n][reg]);
    }
  }
}

// ---------------------------------------------------------------- small GEMM (128x128, attr branch)
__launch_bounds__(256, 2)
__global__ void gemm_bf16_k(const short* __restrict__ A0, const short* __restrict__ A1, int lda,
                            const short* __restrict__ Bt0, const short* __restrict__ Bt1, int ldb,
                            short* __restrict__ C0, short* __restrict__ C1, int ldc, int K,
                            int nbCol, int nbRow) {
  __shared__ short As[128 * 64];
  __shared__ short Bs[128 * 64];

  int orig = blockIdx.x;
  int nwg = gridDim.x;
  int q = nwg >> 3, rr = nwg & 7;
  int xcd = orig & 7, idx = orig >> 3;
  int wg = (xcd < rr ? xcd * (q + 1) : rr * (q + 1) + (xcd - rr) * q) + idx;
  int colB = wg % nbCol;
  int t2   = wg / nbCol;
  int rowB = t2 % nbRow;
  int z    = t2 / nbRow;

  const short* A  = z ? A1 : A0;
  const short* Bt = z ? Bt1 : Bt0;
  short* C        = z ? C1 : C0;

  const int tid  = threadIdx.x;
  const int lane = tid & 63;
  const int wid  = tid >> 6;
  const int wr   = wid >> 1;
  const int wc   = wid & 1;
  const int rowBase = rowB * 128;
  const int colBase = colB * 128;

  const int lrow = lane >> 3;
  const int kofs = (lane & 7) * 8;

  f32x4 acc[4][4];
#pragma unroll
  for (int m = 0; m < 4; ++m)
#pragma unroll
    for (int n = 0; n < 4; ++n)
      acc[m][n] = (f32x4){0.f, 0.f, 0.f, 0.f};

  for (int k0 = 0; k0 < K; k0 += 64) {
#pragma unroll
    for (int c = 0; c < 4; ++c) {
      int chunk = wid * 4 + c;
      int r = chunk * 8 + lrow;
      const short* g = A + (size_t)(rowBase + r) * lda + k0 + kofs;
      GLDS16(g, &As[chunk * 8 * 64]);
    }
#pragma unroll
    for (int c = 0; c < 4; ++c) {
      int chunk = wid * 4 + c;
      int r = chunk * 8 + lrow;
      const short* g = Bt + (size_t)(colBase + r) * ldb + k0 + kofs;
      GLDS16(g, &Bs[chunk * 8 * 64]);
    }
    __syncthreads();

    bf16x8 af[2][4], bfr[2][4];
#pragma unroll
    for (int kk = 0; kk < 2; ++kk) {
#pragma unroll
      for (int i = 0; i < 4; ++i) {
        int ar = wr * 64 + i * 16 + (lane & 15);
        af[kk][i]  = *(const bf16x8*)&As[ar * 64 + kk * 32 + (lane >> 4) * 8];
        int br = wc * 64 + i * 16 + (lane & 15);
        bfr[kk][i] = *(const bf16x8*)&Bs[br * 64 + kk * 32 + (lane >> 4) * 8];
      }
    }
#pragma unroll
    for (int kk = 0; kk < 2; ++kk)
#pragma unroll
      for (int m = 0; m < 4; ++m)
#pragma unroll
        for (int n = 0; n < 4; ++n)
          acc[m][n] = __builtin_amdgcn_mfma_f32_16x16x32_bf16(
              af[kk][m], bfr[kk][n], acc[m][n], 0, 0, 0);
    __syncthreads();
  }

#pragma unroll
  for (int m = 0; m < 4; ++m) {
#pragma unroll
    for (int n = 0; n < 4; ++n) {
      int row0 = rowBase + wr * 64 + m * 16 + (lane >> 4) * 4;
      int col  = colBase + wc * 64 + n * 16 + (lane & 15);
#pragma unroll
      for (int reg = 0; reg < 4; ++reg)
        C[(size_t)(row0 + reg) * ldc + col] = f2bf(acc[m][n][reg]);
    }
  }
}

// ---------------------------------------------------------------- SpMM + ReLU (v5: col-chunked, XCD-pinned)
template<int NCHUNK, int MODE>
__launch_bounds__(256)
__global__ void spmm_v5(const int* __restrict__ po0, const int* __restrict__ po1,
                        const int2* __restrict__ pk0, const int2* __restrict__ pk1,
                        const short* __restrict__ S0, const short* __restrict__ S1, int ldS,
                        short* __restrict__ oB0, short* __restrict__ oB1, int ldB,
                        float* __restrict__ oF0, float* __restrict__ oF1, int outCols) {
  int orig = blockIdx.x;
  int chunk, graph, rowBlk;
  if (NCHUNK == 8) {
    chunk = orig & 7;
    int idx = orig >> 3;
    graph = idx / NRB;
    rowBlk = idx - graph * NRB;
  } else {
    chunk = 0;
    graph = orig / NRB;
    rowBlk = orig - graph * NRB;
  }
  const int* poffs   = graph ? po1 : po0;
  const int2* packed = graph ? pk1 : pk0;
  const short* S     = graph ? S1 : S0;
  short* outB        = graph ? oB1 : oB0;
  float* outF        = graph ? oF1 : oF0;

  const int lane16 = threadIdx.x & 15;
  const int rowloc = threadIdx.x >> 4;
  const int r  = rowBlk * 16 + rowloc;
  const int c0 = chunk * 128 + lane16 * 8;

  int e0 = poffs[r], e1 = poffs[r + 1];
  float acc[8];
#pragma unroll
  for (int j = 0; j < 8; ++j) acc[j] = 0.f;

  for (int i = e0; i < e1; i += 4) {
    const int4* p4 = (const int4*)&packed[i];
    int4 a = p4[0];
    int4 b = p4[1];
    short8v s0 = *(const short8v*)&S[(size_t)a.x * ldS + c0];
    short8v s1 = *(const short8v*)&S[(size_t)a.z * ldS + c0];
    short8v s2 = *(const short8v*)&S[(size_t)b.x * ldS + c0];
    short8v s3 = *(const short8v*)&S[(size_t)b.z * ldS + c0];
    float v0 = __int_as_float(a.y);
    float v1 = __int_as_float(a.w);
    float v2 = __int_as_float(b.y);
    float v3 = __int_as_float(b.w);
#pragma unroll
    for (int j = 0; j < 8; ++j) {
      acc[j] += v0 * bf2f(s0[j]);
      acc[j] += v1 * bf2f(s1[j]);
      acc[j] += v2 * bf2f(s2[j]);
      acc[j] += v3 * bf2f(s3[j]);
    }
  }
#pragma unroll
  for (int j = 0; j < 8; ++j) acc[j] = fmaxf(acc[j], 0.f);

  if (MODE == 0) {
    short8v o;
#pragma unroll
    for (int j = 0; j < 8; ++j) o[j] = f2bf(acc[j]);
    *(short8v*)&outB[(size_t)r * ldB + c0] = o;
  } else {
#pragma unroll
    for (int j = 0; j < 8; ++j)
      if (c0 + j < outCols)
        outF[(size_t)r * outCols + c0 + j] = acc[j];
  }
}

// ---------------------------------------------------------------- row l2 norm (z=2)
__global__ void l2norm2_k(const short* __restrict__ H0, const short* __restrict__ H1, int ldH,
                          float* __restrict__ o0, float* __restrict__ o1, int cols) {
  const short* H = blockIdx.y ? H1 : H0;
  float* out = blockIdx.y ? o1 : o0;
  __shared__ float red[4];
  int r = blockIdx.x;
  int t = threadIdx.x;
  float s = 0.f;
  for (int c = t; c < ldH; c += 256) {
    float v = bf2f(H[(size_t)r * ldH + c]);
    s += v * v;
  }
  for (int off = 32; off >= 1; off >>= 1) s += __shfl_down(s, off, 64);
  if ((t & 63) == 0) red[t >> 6] = s;
  __syncthreads();
  float tot = red[0] + red[1] + red[2] + red[3];
  float inv = 1.f / fmaxf(sqrtf(tot), 1e-12f);
  for (int c = t; c < cols; c += 256)
    out[(size_t)r * cols + c] = bf2f(H[(size_t)r * ldH + c]) * inv;
}

// ---------------------------------------------------------------- launch

extern "C" void kernel_launch(void* const* d_in, const int* in_sizes, int n_in,
                              void* d_out, int out_size, void* d_ws, size_t ws_size,
                              hipStream_t stream) {
  const float* emb_sr  = (const float*)d_in[0];
  const float* emb_tg  = (const float*)d_in[1];
  const float* attr_sr = (const float*)d_in[2];
  const float* attr_tg = (const float*)d_in[3];
  const int*   row_sr  = (const int*)d_in[4];
  const int*   col_sr  = (const int*)d_in[5];
  const float* vals_sr = (const float*)d_in[6];
  const int*   row_tg  = (const int*)d_in[7];
  const int*   col_tg  = (const int*)d_in[8];
  const float* vals_tg = (const float*)d_in[9];
  const float* W_s0    = (const float*)d_in[10];
  const float* W_s1    = (const float*)d_in[11];
  const float* W_a11   = (const float*)d_in[12];
  const float* W_a12   = (const float*)d_in[13];
  const float* W_a2    = (const float*)d_in[14];

  const int N = N_NODES, Dd = D_IN, E = E_EDGES;

  char* ws = (char*)d_ws;
  size_t off = 0;
  auto alloc = [&](size_t bytes) -> void* {
    void* p = ws + off;
    off += (bytes + 255) & ~(size_t)255;
    return p;
  };
  short* X0 = (short*)alloc((size_t)MPAD * DP * 2);
  short* X1 = (short*)alloc((size_t)MPAD * DP * 2);
  short* T0 = (short*)alloc((size_t)MPAD * DP * 2);
  short* T1 = (short*)alloc((size_t)MPAD * DP * 2);
  short* Ws0t  = (short*)alloc((size_t)DP * DP * 2);
  short* Ws1t  = (short*)alloc((size_t)DP * DP * 2);
  short* Wa11t = (short*)alloc((size_t)DAP * DP * 2);
  short* Wa12t = (short*)alloc((size_t)DAP * DP * 2);
  short* Wa2t  = (short*)alloc((size_t)DAP * DAP * 2);
  int*  ibuf    = (int*)alloc((size_t)4 * N * 4);
  int2* pack_sr = (int2*)alloc((size_t)PEMAX * 8);
  int2* pack_tg = (int2*)alloc((size_t)PEMAX * 8);
  int*  poffs_sr = (int*)alloc((size_t)(N + 1) * 4);
  int*  poffs_tg = (int*)alloc((size_t)(N + 1) * 4);
  if (off > ws_size) return;

  int* deg_sr = ibuf;
  int* cur_sr = ibuf + N;
  int* deg_tg = ibuf + 2 * N;
  int* cur_tg = ibuf + 3 * N;
  const int ZERO_N = 4 * N + 2 * (PEMAX * 2);

  float* out_sr  = (float*)d_out;
  float* out_tg  = out_sr + (size_t)N * Dd;
  float* out_sra = out_tg + (size_t)N * Dd;
  float* out_tga = out_sra + (size_t)N * DA;

  // ---- padded-CSR build, both graphs batched
  zero_int_k<<<dim3((ZERO_N + 255) / 256), 256, 0, stream>>>(ibuf, ZERO_N);
  hist2_k<<<dim3((2 * E + 255) / 256), 256, 0, stream>>>(row_sr, row_tg, E, deg_sr, deg_tg);
  scan_pad2_k<<<2, SCAN_T, 0, stream>>>(deg_sr, deg_tg, N, poffs_sr, poffs_tg);
  scatter_pack2_k<<<dim3((2 * E + 255) / 256), 256, 0, stream>>>(
      row_sr, col_sr, vals_sr, row_tg, col_tg, vals_tg, E,
      poffs_sr, poffs_tg, cur_sr, cur_tg, pack_sr, pack_tg);

  // ---- weight conversions (transposed + padded), batched
  cvt_w_t2_k<<<dim3(DP / 256, DP, 2), 256, 0, stream>>>(W_s0, W_s1, Dd, Dd, Ws0t, Ws1t, DP);
  cvt_w_t2_k<<<dim3(DP / 256, DAP, 2), 256, 0, stream>>>(W_a11, W_a12, Dd, DA, Wa11t, Wa12t, DP);
  cvt_w_t2_k<<<dim3(1, DAP, 1), 256, 0, stream>>>(W_a2, W_a2, DA, DA, Wa2t, Wa2t, DAP);

  // ---- structural branch: 8-phase 256^2 GEMM (79x4x2 = 632 blocks, %8==0)
  cvt_pad2_k<<<dim3(1, MPAD, 2), 256, 0, stream>>>(emb_sr, emb_tg, N, Dd, X0, X1, DP);
  gemm8p_k<<<dim3(79 * 4 * 2), 512, 0, stream>>>(X0, X1, DP, Ws0t, Ws0t, DP,
                                                 T0, T1, DP, 4, 79);
  spmm_v5<8, 0><<<dim3(8 * 2 * NRB), 256, 0, stream>>>(
      poffs_sr, poffs_tg, pack_sr, pack_tg, T0, T1, DP, X0, X1, DP, nullptr, nullptr, 0);
  gemm8p_k<<<dim3(79 * 4 * 2), 512, 0, stream>>>(X0, X1, DP, Ws1t, Ws1t, DP,
                                                 T0, T1, DP, 4, 79);
  spmm_v5<8, 0><<<dim3(8 * 2 * NRB), 256, 0, stream>>>(
      poffs_sr, poffs_tg, pack_sr, pack_tg, T0, T1, DP, X0, X1, DP, nullptr, nullptr, 0);
  l2norm2_k<<<dim3(N, 2), 256, 0, stream>>>(X0, X1, DP, out_sr, out_tg, Dd);

  // ---- attribute branch (compact stride DAP after first GEMM)
  cvt_pad2_k<<<dim3(1, MPAD, 2), 256, 0, stream>>>(attr_sr, attr_tg, N, Dd, X0, X1, DP);
  gemm_bf16_k<<<dim3(1 * MBLK * 2), 256, 0, stream>>>(X0, X1, DP, Wa11t, Wa12t, DP,
                                                      T0, T1, DAP, DP, 1, MBLK);
  spmm_v5<1, 0><<<dim3(2 * NRB), 256, 0, stream>>>(
      poffs_sr, poffs_tg, pack_sr, pack_tg, T0, T1, DAP, X0, X1, DAP, nullptr, nullptr, 0);
  gemm_bf16_k<<<dim3(1 * MBLK * 2), 256, 0, stream>>>(X0, X1, DAP, Wa2t, Wa2t, DAP,
                                                      T0, T1, DAP, DAP, 1, MBLK);
  spmm_v5<1, 1><<<dim3(2 * NRB), 256, 0, stream>>>(
      poffs_sr, poffs_tg, pack_sr, pack_tg, T0, T1, DAP, nullptr, nullptr, 0, out_sra, out_tga, DA);
}

// Round 9
// 635.107 us; speedup vs baseline: 1.0341x; 1.0029x over previous
//
#include <hip/hip_runtime.h>

#define N_NODES 20000
#define D_IN    1000
#define E_EDGES 160000
#define DA      100

#define MPAD 20224    // 79 * 256 (padded rows for 256-tile GEMM)
#define DP   1024     // padded K / structural cols
#define DAP  128      // padded attr cols
#define MBLK 157      // 128-row blocks for attr gemm
#define NRB  1250     // row-blocks per graph for spmm (16 rows/block)
#define PEMAX (E_EDGES + 4 * N_NODES)   // padded edge capacity (rows padded to x4)

typedef __bf16 bf16x8 __attribute__((ext_vector_type(8)));
typedef float  f32x4  __attribute__((ext_vector_type(4)));
typedef short  short8v __attribute__((ext_vector_type(8)));

__device__ __forceinline__ short f2bf(float f) {
  __bf16 h = (__bf16)f;                 // native RNE cvt
  return *(short*)&h;
}
__device__ __forceinline__ float bf2f(short s) {
  return __uint_as_float(((unsigned)(unsigned short)s) << 16);
}

#define GLDS16(g, l) __builtin_amdgcn_global_load_lds( \
    (const __attribute__((address_space(1))) void*)(g), \
    (__attribute__((address_space(3))) void*)(l), 16, 0, 0)

// ---------------------------------------------------------------- conversions

// batched (z=4) f32->bf16 pad, float4 loads. grid: (1, MPAD, 4), 256 thr
__global__ void cvt_pad4_k(const float* __restrict__ s0, const float* __restrict__ s1,
                           const float* __restrict__ s2, const float* __restrict__ s3,
                           int R, int C,
                           short* __restrict__ d0, short* __restrict__ d1,
                           short* __restrict__ d2, short* __restrict__ d3, int Cp) {
  const float* src; short* dst;
  switch (blockIdx.z) {
    case 0:  src = s0; dst = d0; break;
    case 1:  src = s1; dst = d1; break;
    case 2:  src = s2; dst = d2; break;
    default: src = s3; dst = d3; break;
  }
  int r = blockIdx.y;
  int c0 = threadIdx.x * 4;
  short4 o = {0, 0, 0, 0};
  if (r < R) {
    if (c0 + 3 < C) {
      float4 v = *(const float4*)&src[(size_t)r * C + c0];
      o.x = f2bf(v.x); o.y = f2bf(v.y); o.z = f2bf(v.z); o.w = f2bf(v.w);
    } else {
#pragma unroll
      for (int j = 0; j < 4; ++j) {
        float v = (c0 + j < C) ? src[(size_t)r * C + c0 + j] : 0.f;
        ((short*)&o)[j] = f2bf(v);
      }
    }
  }
  *(short4*)&dst[(size_t)r * Cp + c0] = o;
}

__global__ void cvt_w_t2_k(const float* __restrict__ s0, const float* __restrict__ s1,
                           int K, int Nc,
                           short* __restrict__ d0, short* __restrict__ d1, int Kp) {
  const float* src = blockIdx.z ? s1 : s0;
  short* dst = blockIdx.z ? d1 : d0;
  int n = blockIdx.y;
  int k = blockIdx.x * blockDim.x + threadIdx.x;
  if (k >= Kp) return;
  float v = (k < K && n < Nc) ? src[(size_t)k * Nc + n] : 0.f;
  dst[(size_t)n * Kp + k] = f2bf(v);
}

__global__ void zero_int_k(int* p, int n) {
  int i = blockIdx.x * blockDim.x + threadIdx.x;
  if (i < n) p[i] = 0;
}

// ---------------------------------------------------------------- CSR build (padded, both graphs)

__global__ void hist2_k(const int* __restrict__ row0, const int* __restrict__ row1, int E,
                        int* __restrict__ deg0, int* __restrict__ deg1) {
  int e = blockIdx.x * blockDim.x + threadIdx.x;
  if (e < E) atomicAdd(&deg0[row0[e]], 1);
  else if (e < 2 * E) atomicAdd(&deg1[row1[e - E]], 1);
}

#define SCAN_T 1024
#define SCAN_C 20
__launch_bounds__(SCAN_T)
__global__ void scan_pad2_k(const int* __restrict__ dg0, const int* __restrict__ dg1, int n,
                            int* __restrict__ p0, int* __restrict__ p1) {
  const int* deg = blockIdx.x ? dg1 : dg0;
  int* poffs = blockIdx.x ? p1 : p0;
  __shared__ int lds[SCAN_T];
  int t = threadIdx.x;
  int base = t * SCAN_C;
  int v[SCAN_C];
  int s = 0;
#pragma unroll
  for (int i = 0; i < SCAN_C; ++i) {
    int idx = base + i;
    int x = (idx < n) ? ((deg[idx] + 3) & ~3) : 0;
    s += x;
    v[i] = s;
  }
  lds[t] = s;
  __syncthreads();
  for (int off = 1; off < SCAN_T; off <<= 1) {
    int add = (t >= off) ? lds[t - off] : 0;
    __syncthreads();
    lds[t] += add;
    __syncthreads();
  }
  int prefix = lds[t] - s;
#pragma unroll
  for (int i = 0; i < SCAN_C; ++i) {
    int idx = base + i;
    if (idx < n) poffs[idx + 1] = v[i] + prefix;
  }
  if (t == 0) poffs[0] = 0;
}

__global__ void scatter_pack2_k(const int* __restrict__ row0, const int* __restrict__ col0,
                                const float* __restrict__ val0,
                                const int* __restrict__ row1, const int* __restrict__ col1,
                                const float* __restrict__ val1, int E,
                                const int* __restrict__ po0, const int* __restrict__ po1,
                                int* __restrict__ cur0, int* __restrict__ cur1,
                                int2* __restrict__ pk0, int2* __restrict__ pk1) {
  int e = blockIdx.x * blockDim.x + threadIdx.x;
  if (e < E) {
    int r = row0[e];
    int p = atomicAdd(&cur0[r], 1);
    pk0[po0[r] + p] = make_int2(col0[e], __float_as_int(val0[e]));
  } else if (e < 2 * E) {
    int ee = e - E;
    int r = row1[ee];
    int p = atomicAdd(&cur1[r], 1);
    pk1[po1[r] + p] = make_int2(col1[ee], __float_as_int(val1[ee]));
  }
}

// ---------------------------------------------------------------- 8-phase 256x256 GEMM (structural)
// v2 (r9): B-frag register reuse across QM phases (24 instead of 32 ds_read /
// wave / K-tile); vmcnt waits only at odd phases (2 / K-tile, m201-style);
// no sched_barrier (m141: order-pinning hurts). Wait-schedule derivation:
// phase p reads halves <= p+1; wait at end of p-1 with vmcnt(6) guarantees
// H_{<= (p-1)+5-3} = H_{p+1} landed. Tail: vmcnt(6)@t14P1, (4)@t14P3, (0)@t15P1.
__launch_bounds__(512, 1)
__global__ void gemm8p_k(const short* __restrict__ A0, const short* __restrict__ A1, int lda,
                         const short* __restrict__ Bt0, const short* __restrict__ Bt1, int ldb,
                         short* __restrict__ C0, short* __restrict__ C1, int ldc,
                         int nbCol, int nbRow) {
  __shared__ short lds[8][8192];   // 8 x 16 KB = 128 KB

  // XCD-aware bijective remap (cols fastest within chunk)
  int orig = blockIdx.x;
  int nwg = gridDim.x;
  int q = nwg >> 3, rr = nwg & 7;
  int xcd = orig & 7, idx = orig >> 3;
  int wg = (xcd < rr ? xcd * (q + 1) : rr * (q + 1) + (xcd - rr) * q) + idx;
  int colB = wg % nbCol;
  int t2 = wg / nbCol;
  int rowB = t2 % nbRow;
  int z = t2 / nbRow;

  const short* A  = z ? A1 : A0;
  const short* Bt = z ? Bt1 : Bt0;
  short* C        = z ? C1 : C0;

  const int tid  = threadIdx.x;
  const int lane = tid & 63;
  const int wid  = tid >> 6;
  const int wm   = wid >> 2;      // 0..1
  const int wn   = wid & 3;       // 0..3
  const int rowBase = rowB * 256;
  const int colBase = colB * 256;

  // stage source: lane -> local row l>>2, chunk (l&3)^((l>>3)&3) (pre-swizzled)
  const int sC = (lane & 3) ^ ((lane >> 3) & 3);
  const short* baseA = A  + (size_t)(rowBase + wid * 32 + (lane >> 2)) * lda + sC * 8;
  const short* baseB = Bt + (size_t)(colBase + wid * 32 + (lane >> 2)) * ldb + sC * 8;

  // read-side swizzled offsets (shorts within a 16 KB slot: [256 rows][32 cols])
  const int chunkR = (lane >> 4) ^ ((lane >> 1) & 3);
  const int offA = (wm * 128 + (lane & 15)) * 32 + chunkR * 8;
  const int offB = (wn * 64  + (lane & 15)) * 32 + chunkR * 8;

  f32x4 acc[8][4];
#pragma unroll
  for (int m = 0; m < 8; ++m)
#pragma unroll
    for (int n = 0; n < 4; ++n)
      acc[m][n] = (f32x4){0.f, 0.f, 0.f, 0.f};

#define STAGE_HALF(h) do { \
    int tt_ = (h) >> 2; \
    int kc_ = tt_ * 64 + (((h) >> 1) & 1) * 32; \
    short* dst_ = &lds[(h) & 7][wid * 1024]; \
    if ((h) & 1) { GLDS16(baseB + kc_, dst_); GLDS16(baseB + kc_ + 16 * ldb, dst_ + 512); } \
    else         { GLDS16(baseA + kc_, dst_); GLDS16(baseA + kc_ + 16 * lda, dst_ + 512); } \
  } while (0)

  // prologue: stage H0..H4, wait so H0,H1 landed (leave 3 halves = 6 loads)
  STAGE_HALF(0); STAGE_HALF(1); STAGE_HALF(2); STAGE_HALF(3); STAGE_HALF(4);
  asm volatile("s_waitcnt vmcnt(6)" ::: "memory");
  __builtin_amdgcn_s_barrier();

  bf16x8 bv[4];
  for (int t = 0; t < 16; ++t) {
    const int s0 = (4 * t) & 7;
    const int s1 = (4 * t + 2) & 7;

    // ---- P0: ks=0, qm=0 (loads B for the ks0 pair)
    {
      const short* pA = &lds[s0][0];
      const short* pB = &lds[s0 + 1][0];
      bf16x8 af[4];
#pragma unroll
      for (int n = 0; n < 4; ++n) bv[n] = *(const bf16x8*)&pB[offB + n * 512];
#pragma unroll
      for (int m = 0; m < 4; ++m) af[m] = *(const bf16x8*)&pA[offA + m * 512];
      { int h = 4 * t + 5; if (h < 64) STAGE_HALF(h); }
      __builtin_amdgcn_s_barrier();
      __builtin_amdgcn_s_setprio(1);
#pragma unroll
      for (int m = 0; m < 4; ++m)
#pragma unroll
        for (int n = 0; n < 4; ++n)
          acc[m][n] = __builtin_amdgcn_mfma_f32_16x16x32_bf16(af[m], bv[n], acc[m][n], 0, 0, 0);
      __builtin_amdgcn_s_setprio(0);
      __builtin_amdgcn_s_barrier();
    }
    // ---- P1: ks=0, qm=1 (B reused from regs)
    {
      const short* pA = &lds[s0][0];
      bf16x8 af[4];
#pragma unroll
      for (int m = 0; m < 4; ++m) af[m] = *(const bf16x8*)&pA[offA + (4 + m) * 512];
      { int h = 4 * t + 6; if (h < 64) STAGE_HALF(h); }
      __builtin_amdgcn_s_barrier();
      __builtin_amdgcn_s_setprio(1);
#pragma unroll
      for (int m = 0; m < 4; ++m)
#pragma unroll
        for (int n = 0; n < 4; ++n)
          acc[4 + m][n] = __builtin_amdgcn_mfma_f32_16x16x32_bf16(af[m], bv[n], acc[4 + m][n], 0, 0, 0);
      __builtin_amdgcn_s_setprio(0);
      if (t < 15) { asm volatile("s_waitcnt vmcnt(6)" ::: "memory"); }
      else        { asm volatile("s_waitcnt vmcnt(0)" ::: "memory"); }
      __builtin_amdgcn_s_barrier();
    }
    // ---- P2: ks=1, qm=0
    {
      const short* pA = &lds[s1][0];
      const short* pB = &lds[s1 + 1][0];
      bf16x8 af[4];
#pragma unroll
      for (int n = 0; n < 4; ++n) bv[n] = *(const bf16x8*)&pB[offB + n * 512];
#pragma unroll
      for (int m = 0; m < 4; ++m) af[m] = *(const bf16x8*)&pA[offA + m * 512];
      { int h = 4 * t + 7; if (h < 64) STAGE_HALF(h); }
      __builtin_amdgcn_s_barrier();
      __builtin_amdgcn_s_setprio(1);
#pragma unroll
      for (int m = 0; m < 4; ++m)
#pragma unroll
        for (int n = 0; n < 4; ++n)
          acc[m][n] = __builtin_amdgcn_mfma_f32_16x16x32_bf16(af[m], bv[n], acc[m][n], 0, 0, 0);
      __builtin_amdgcn_s_setprio(0);
      __builtin_amdgcn_s_barrier();
    }
    // ---- P3: ks=1, qm=1
    {
      const short* pA = &lds[s1][0];
      bf16x8 af[4];
#pragma unroll
      for (int m = 0; m < 4; ++m) af[m] = *(const bf16x8*)&pA[offA + (4 + m) * 512];
      { int h = 4 * t + 8; if (h < 64) STAGE_HALF(h); }
      __builtin_amdgcn_s_barrier();
      __builtin_amdgcn_s_setprio(1);
#pragma unroll
      for (int m = 0; m < 4; ++m)
#pragma unroll
        for (int n = 0; n < 4; ++n)
          acc[4 + m][n] = __builtin_amdgcn_mfma_f32_16x16x32_bf16(af[m], bv[n], acc[4 + m][n], 0, 0, 0);
      __builtin_amdgcn_s_setprio(0);
      if (t < 14)       { asm volatile("s_waitcnt vmcnt(6)" ::: "memory"); }
      else if (t == 14) { asm volatile("s_waitcnt vmcnt(4)" ::: "memory"); }
      __builtin_amdgcn_s_barrier();
    }
  }
#undef STAGE_HALF

  // C write: D layout col=lane&15, row=(lane>>4)*4+reg
#pragma unroll
  for (int gm = 0; gm < 8; ++gm) {
#pragma unroll
    for (int n = 0; n < 4; ++n) {
      int r0 = rowBase + wm * 128 + gm * 16 + (lane >> 4) * 4;
      int c  = colBase + wn * 64 + n * 16 + (lane & 15);
#pragma unroll
      for (int reg = 0; reg < 4; ++reg)
        C[(size_t)(r0 + reg) * ldc + c] = f2bf(acc[gm][n][reg]);
    }
  }
}

// ---------------------------------------------------------------- small GEMM (128x128, attr branch)
__launch_bounds__(256, 2)
__global__ void gemm_bf16_k(const short* __restrict__ A0, const short* __restrict__ A1, int lda,
                            const short* __restrict__ Bt0, const short* __restrict__ Bt1, int ldb,
                            short* __restrict__ C0, short* __restrict__ C1, int ldc, int K,
                            int nbCol, int nbRow) {
  __shared__ short As[128 * 64];
  __shared__ short Bs[128 * 64];

  int orig = blockIdx.x;
  int nwg = gridDim.x;
  int q = nwg >> 3, rr = nwg & 7;
  int xcd = orig & 7, idx = orig >> 3;
  int wg = (xcd < rr ? xcd * (q + 1) : rr * (q + 1) + (xcd - rr) * q) + idx;
  int colB = wg % nbCol;
  int t2   = wg / nbCol;
  int rowB = t2 % nbRow;
  int z    = t2 / nbRow;

  const short* A  = z ? A1 : A0;
  const short* Bt = z ? Bt1 : Bt0;
  short* C        = z ? C1 : C0;

  const int tid  = threadIdx.x;
  const int lane = tid & 63;
  const int wid  = tid >> 6;
  const int wr   = wid >> 1;
  const int wc   = wid & 1;
  const int rowBase = rowB * 128;
  const int colBase = colB * 128;

  const int lrow = lane >> 3;
  const int kofs = (lane & 7) * 8;

  f32x4 acc[4][4];
#pragma unroll
  for (int m = 0; m < 4; ++m)
#pragma unroll
    for (int n = 0; n < 4; ++n)
      acc[m][n] = (f32x4){0.f, 0.f, 0.f, 0.f};

  for (int k0 = 0; k0 < K; k0 += 64) {
#pragma unroll
    for (int c = 0; c < 4; ++c) {
      int chunk = wid * 4 + c;
      int r = chunk * 8 + lrow;
      const short* g = A + (size_t)(rowBase + r) * lda + k0 + kofs;
      GLDS16(g, &As[chunk * 8 * 64]);
    }
#pragma unroll
    for (int c = 0; c < 4; ++c) {
      int chunk = wid * 4 + c;
      int r = chunk * 8 + lrow;
      const short* g = Bt + (size_t)(colBase + r) * ldb + k0 + kofs;
      GLDS16(g, &Bs[chunk * 8 * 64]);
    }
    __syncthreads();

    bf16x8 af[2][4], bfr[2][4];
#pragma unroll
    for (int kk = 0; kk < 2; ++kk) {
#pragma unroll
      for (int i = 0; i < 4; ++i) {
        int ar = wr * 64 + i * 16 + (lane & 15);
        af[kk][i]  = *(const bf16x8*)&As[ar * 64 + kk * 32 + (lane >> 4) * 8];
        int br = wc * 64 + i * 16 + (lane & 15);
        bfr[kk][i] = *(const bf16x8*)&Bs[br * 64 + kk * 32 + (lane >> 4) * 8];
      }
    }
#pragma unroll
    for (int kk = 0; kk < 2; ++kk)
#pragma unroll
      for (int m = 0; m < 4; ++m)
#pragma unroll
        for (int n = 0; n < 4; ++n)
          acc[m][n] = __builtin_amdgcn_mfma_f32_16x16x32_bf16(
              af[kk][m], bfr[kk][n], acc[m][n], 0, 0, 0);
    __syncthreads();
  }

#pragma unroll
  for (int m = 0; m < 4; ++m) {
#pragma unroll
    for (int n = 0; n < 4; ++n) {
      int row0 = rowBase + wr * 64 + m * 16 + (lane >> 4) * 4;
      int col  = colBase + wc * 64 + n * 16 + (lane & 15);
#pragma unroll
      for (int reg = 0; reg < 4; ++reg)
        C[(size_t)(row0 + reg) * ldc + col] = f2bf(acc[m][n][reg]);
    }
  }
}

// ---------------------------------------------------------------- SpMM + ReLU (v5: col-chunked, XCD-pinned)
template<int NCHUNK, int MODE>
__launch_bounds__(256)
__global__ void spmm_v5(const int* __restrict__ po0, const int* __restrict__ po1,
                        const int2* __restrict__ pk0, const int2* __restrict__ pk1,
                        const short* __restrict__ S0, const short* __restrict__ S1, int ldS,
                        short* __restrict__ oB0, short* __restrict__ oB1, int ldB,
                        float* __restrict__ oF0, float* __restrict__ oF1, int outCols) {
  int orig = blockIdx.x;
  int chunk, graph, rowBlk;
  if (NCHUNK == 8) {
    chunk = orig & 7;
    int idx = orig >> 3;
    graph = idx / NRB;
    rowBlk = idx - graph * NRB;
  } else {
    chunk = 0;
    graph = orig / NRB;
    rowBlk = orig - graph * NRB;
  }
  const int* poffs   = graph ? po1 : po0;
  const int2* packed = graph ? pk1 : pk0;
  const short* S     = graph ? S1 : S0;
  short* outB        = graph ? oB1 : oB0;
  float* outF        = graph ? oF1 : oF0;

  const int lane16 = threadIdx.x & 15;
  const int rowloc = threadIdx.x >> 4;
  const int r  = rowBlk * 16 + rowloc;
  const int c0 = chunk * 128 + lane16 * 8;

  int e0 = poffs[r], e1 = poffs[r + 1];
  float acc[8];
#pragma unroll
  for (int j = 0; j < 8; ++j) acc[j] = 0.f;

  for (int i = e0; i < e1; i += 4) {
    const int4* p4 = (const int4*)&packed[i];
    int4 a = p4[0];
    int4 b = p4[1];
    short8v s0 = *(const short8v*)&S[(size_t)a.x * ldS + c0];
    short8v s1 = *(const short8v*)&S[(size_t)a.z * ldS + c0];
    short8v s2 = *(const short8v*)&S[(size_t)b.x * ldS + c0];
    short8v s3 = *(const short8v*)&S[(size_t)b.z * ldS + c0];
    float v0 = __int_as_float(a.y);
    float v1 = __int_as_float(a.w);
    float v2 = __int_as_float(b.y);
    float v3 = __int_as_float(b.w);
#pragma unroll
    for (int j = 0; j < 8; ++j) {
      acc[j] += v0 * bf2f(s0[j]);
      acc[j] += v1 * bf2f(s1[j]);
      acc[j] += v2 * bf2f(s2[j]);
      acc[j] += v3 * bf2f(s3[j]);
    }
  }
#pragma unroll
  for (int j = 0; j < 8; ++j) acc[j] = fmaxf(acc[j], 0.f);

  if (MODE == 0) {
    short8v o;
#pragma unroll
    for (int j = 0; j < 8; ++j) o[j] = f2bf(acc[j]);
    *(short8v*)&outB[(size_t)r * ldB + c0] = o;
  } else {
#pragma unroll
    for (int j = 0; j < 8; ++j)
      if (c0 + j < outCols)
        outF[(size_t)r * outCols + c0 + j] = acc[j];
  }
}

// ---------------------------------------------------------------- row l2 norm (z=2), vectorized short4 reads
__launch_bounds__(256)
__global__ void l2norm2_k(const short* __restrict__ H0, const short* __restrict__ H1, int ldH,
                          float* __restrict__ o0, float* __restrict__ o1, int cols) {
  const short* H = blockIdx.y ? H1 : H0;
  float* out = blockIdx.y ? o1 : o0;
  __shared__ float red[4];
  int r = blockIdx.x;
  int t = threadIdx.x;
  // 256 thr x short4 = 1024 cols in one vector load
  short4 v = ((const short4*)(H + (size_t)r * ldH))[t];
  float f0 = bf2f(v.x), f1 = bf2f(v.y), f2 = bf2f(v.z), f3 = bf2f(v.w);
  float s = f0 * f0 + f1 * f1 + f2 * f2 + f3 * f3;
  for (int off = 32; off >= 1; off >>= 1) s += __shfl_down(s, off, 64);
  if ((t & 63) == 0) red[t >> 6] = s;
  __syncthreads();
  float tot = red[0] + red[1] + red[2] + red[3];
  float inv = 1.f / fmaxf(sqrtf(tot), 1e-12f);
  int c0 = t * 4;
  float vals[4] = {f0, f1, f2, f3};
#pragma unroll
  for (int j = 0; j < 4; ++j)
    if (c0 + j < cols)
      out[(size_t)r * cols + c0 + j] = vals[j] * inv;
}

// ---------------------------------------------------------------- launch

extern "C" void kernel_launch(void* const* d_in, const int* in_sizes, int n_in,
                              void* d_out, int out_size, void* d_ws, size_t ws_size,
                              hipStream_t stream) {
  const float* emb_sr  = (const float*)d_in[0];
  const float* emb_tg  = (const float*)d_in[1];
  const float* attr_sr = (const float*)d_in[2];
  const float* attr_tg = (const float*)d_in[3];
  const int*   row_sr  = (const int*)d_in[4];
  const int*   col_sr  = (const int*)d_in[5];
  const float* vals_sr = (const float*)d_in[6];
  const int*   row_tg  = (const int*)d_in[7];
  const int*   col_tg  = (const int*)d_in[8];
  const float* vals_tg = (const float*)d_in[9];
  const float* W_s0    = (const float*)d_in[10];
  const float* W_s1    = (const float*)d_in[11];
  const float* W_a11   = (const float*)d_in[12];
  const float* W_a12   = (const float*)d_in[13];
  const float* W_a2    = (const float*)d_in[14];

  const int N = N_NODES, Dd = D_IN, E = E_EDGES;

  char* ws = (char*)d_ws;
  size_t off = 0;
  auto alloc = [&](size_t bytes) -> void* {
    void* p = ws + off;
    off += (bytes + 255) & ~(size_t)255;
    return p;
  };
  short* X0 = (short*)alloc((size_t)MPAD * DP * 2);
  short* X1 = (short*)alloc((size_t)MPAD * DP * 2);
  short* T0 = (short*)alloc((size_t)MPAD * DP * 2);
  short* T1 = (short*)alloc((size_t)MPAD * DP * 2);
  short* Y0 = (short*)alloc((size_t)MPAD * DP * 2);   // attr bf16 (early convert)
  short* Y1 = (short*)alloc((size_t)MPAD * DP * 2);
  short* Ws0t  = (short*)alloc((size_t)DP * DP * 2);
  short* Ws1t  = (short*)alloc((size_t)DP * DP * 2);
  short* Wa11t = (short*)alloc((size_t)DAP * DP * 2);
  short* Wa12t = (short*)alloc((size_t)DAP * DP * 2);
  short* Wa2t  = (short*)alloc((size_t)DAP * DAP * 2);
  int*  ibuf    = (int*)alloc((size_t)4 * N * 4);
  int2* pack_sr = (int2*)alloc((size_t)PEMAX * 8);
  int2* pack_tg = (int2*)alloc((size_t)PEMAX * 8);
  int*  poffs_sr = (int*)alloc((size_t)(N + 1) * 4);
  int*  poffs_tg = (int*)alloc((size_t)(N + 1) * 4);
  if (off > ws_size) return;

  int* deg_sr = ibuf;
  int* cur_sr = ibuf + N;
  int* deg_tg = ibuf + 2 * N;
  int* cur_tg = ibuf + 3 * N;
  const int ZERO_N = 4 * N + 2 * (PEMAX * 2);

  float* out_sr  = (float*)d_out;
  float* out_tg  = out_sr + (size_t)N * Dd;
  float* out_sra = out_tg + (size_t)N * Dd;
  float* out_tga = out_sra + (size_t)N * DA;

  // ---- padded-CSR build, both graphs batched
  zero_int_k<<<dim3((ZERO_N + 255) / 256), 256, 0, stream>>>(ibuf, ZERO_N);
  hist2_k<<<dim3((2 * E + 255) / 256), 256, 0, stream>>>(row_sr, row_tg, E, deg_sr, deg_tg);
  scan_pad2_k<<<2, SCAN_T, 0, stream>>>(deg_sr, deg_tg, N, poffs_sr, poffs_tg);
  scatter_pack2_k<<<dim3((2 * E + 255) / 256), 256, 0, stream>>>(
      row_sr, col_sr, vals_sr, row_tg, col_tg, vals_tg, E,
      poffs_sr, poffs_tg, cur_sr, cur_tg, pack_sr, pack_tg);

  // ---- all input conversions up front (z=4 batch) + weights
  cvt_pad4_k<<<dim3(1, MPAD, 4), 256, 0, stream>>>(emb_sr, emb_tg, attr_sr, attr_tg,
                                                   N, Dd, X0, X1, Y0, Y1, DP);
  cvt_w_t2_k<<<dim3(DP / 256, DP, 2), 256, 0, stream>>>(W_s0, W_s1, Dd, Dd, Ws0t, Ws1t, DP);
  cvt_w_t2_k<<<dim3(DP / 256, DAP, 2), 256, 0, stream>>>(W_a11, W_a12, Dd, DA, Wa11t, Wa12t, DP);
  cvt_w_t2_k<<<dim3(1, DAP, 1), 256, 0, stream>>>(W_a2, W_a2, DA, DA, Wa2t, Wa2t, DAP);

  // ---- structural branch: 8-phase 256^2 GEMM (79x4x2 = 632 blocks)
  gemm8p_k<<<dim3(79 * 4 * 2), 512, 0, stream>>>(X0, X1, DP, Ws0t, Ws0t, DP,
                                                 T0, T1, DP, 4, 79);
  spmm_v5<8, 0><<<dim3(8 * 2 * NRB), 256, 0, stream>>>(
      poffs_sr, poffs_tg, pack_sr, pack_tg, T0, T1, DP, X0, X1, DP, nullptr, nullptr, 0);
  gemm8p_k<<<dim3(79 * 4 * 2), 512, 0, stream>>>(X0, X1, DP, Ws1t, Ws1t, DP,
                                                 T0, T1, DP, 4, 79);
  spmm_v5<8, 0><<<dim3(8 * 2 * NRB), 256, 0, stream>>>(
      poffs_sr, poffs_tg, pack_sr, pack_tg, T0, T1, DP, X0, X1, DP, nullptr, nullptr, 0);
  l2norm2_k<<<dim3(N, 2), 256, 0, stream>>>(X0, X1, DP, out_sr, out_tg, Dd);

  // ---- attribute branch (A = Y, pre-converted; compact stride DAP)
  gemm_bf16_k<<<dim3(1 * MBLK * 2), 256, 0, stream>>>(Y0, Y1, DP, Wa11t, Wa12t, DP,
                                                      T0, T1, DAP, DP, 1, MBLK);
  spmm_v5<1, 0><<<dim3(2 * NRB), 256, 0, stream>>>(
      poffs_sr, poffs_tg, pack_sr, pack_tg, T0, T1, DAP, X0, X1, DAP, nullptr, nullptr, 0);
  gemm_bf16_k<<<dim3(1 * MBLK * 2), 256, 0, stream>>>(X0, X1, DAP, Wa2t, Wa2t, DAP,
                                                      T0, T1, DAP, DAP, 1, MBLK);
  spmm_v5<1, 1><<<dim3(2 * NRB), 256, 0, stream>>>(
      poffs_sr, poffs_tg, pack_sr, pack_tg, T0, T1, DAP, nullptr, nullptr, 0, out_sra, out_tga, DA);
}